// Round 10
// baseline (152.091 us; speedup 1.0000x reference)
//
#include <hip/hip_runtime.h>

// GDAttention: B=8, S=2048, D=256, H=8.
// out[b,q,d] = (1/(q+1)) * softmax(clip(QK^T/16))·E @ Wsum^T,  Wsum[d][d'] = sum_h W_o[d][h*256+d'].
// Clip-before-softmax => no running max; softmax partials are purely additive.
//
// R9 = R8 with the LDS sizing bug fixed: a 32x256 bf16 tile is 16KB (not 8KB).
// Buffer = K 16KB + E 16KB = 32KB, double-buffered = 64KB; stage_tile copies the FULL
// 16KB per operand (j<4). Shared LDS staging via global_load_lds (wave-uniform dest),
// counted waits so staging flies across the mid-iter P barrier. 32-row q-tile,
// 4 waves = (q-half x work-half). Grid 512 (2 blocks/CU), pairing t32 = pr<32 ? pr : 95-pr.
// Batch<->XCD: b = bid&7.

typedef __attribute__((ext_vector_type(8))) short short8;   // 8 x bf16 (4 VGPRs) MFMA frag
typedef __attribute__((ext_vector_type(4))) float f32x4;    // MFMA 16x16 accumulator

__device__ __forceinline__ unsigned short f2b(float x) {    // f32 -> bf16 (round-to-nearest-even)
  unsigned u = __builtin_bit_cast(unsigned, x);
  u = (u + 0x7fffu + ((u >> 16) & 1u)) >> 16;
  return (unsigned short)u;
}

#define GLOAD_LDS16(gp, lp)                                                                        \
  __builtin_amdgcn_global_load_lds((const __attribute__((address_space(1))) unsigned int*)(gp),    \
                                   (__attribute__((address_space(3))) unsigned int*)(lp), 16, 0, 0)

// ---------- pre-pass 1: p (f32 [8][2049][256]) -> bf16, same layout (Q source) ----------
__global__ void cvt_p_kernel(const float* __restrict__ src, unsigned short* __restrict__ dst) {
  size_t t = (size_t)blockIdx.x * 256 + threadIdx.x;  // 524544 threads, 8 elems each
  const float4* s = (const float4*)(src + t * 8);
  float4 a = s[0], b = s[1];
  short8 o;
  o[0] = (short)f2b(a.x); o[1] = (short)f2b(a.y); o[2] = (short)f2b(a.z); o[3] = (short)f2b(a.w);
  o[4] = (short)f2b(b.x); o[5] = (short)f2b(b.y); o[6] = (short)f2b(b.z); o[7] = (short)f2b(b.w);
  *(short8*)(dst + t * 8) = o;
}

// ---------- pre-pass 2: e -> B-fragment-ready bf16 ----------
// chunk (b,kt) elem ((d0*64 + lane)*8 + i) = e[b][kt*32 + (lane>>4)*8 + i][d0*16 + (lane&15)]
__global__ void perm_e_kernel(const float* __restrict__ e, unsigned short* __restrict__ dst) {
  size_t t = (size_t)blockIdx.x * 256 + threadIdx.x;  // 524288 threads
  int lane = (int)(t & 63);
  int d0 = (int)((t >> 6) & 15);
  int kt = (int)((t >> 10) & 63);
  int b = (int)(t >> 16);
  int g = lane >> 4, l = lane & 15;
  const float* s = e + ((size_t)b * 2048 + kt * 32 + g * 8) * 256 + d0 * 16 + l;
  short8 o;
#pragma unroll
  for (int i = 0; i < 8; ++i) o[i] = (short)f2b(s[(size_t)i * 256]);
  *(short8*)(dst + t * 8) = o;
}

// ---------- pre-pass 2b: K (= p[:, :-1, :]) -> B-fragment-ready bf16 ----------
// chunk (b,kt) elem (((kc*2+n0)*64 + lane)*8 + i) = p[b][kt*32 + n0*16 + (lane&15)][kc*32 + (lane>>4)*8 + i]
__global__ void perm_k_kernel(const float* __restrict__ p, unsigned short* __restrict__ dst) {
  size_t t = (size_t)blockIdx.x * 256 + threadIdx.x;  // 524288 threads
  int lane = (int)(t & 63);
  int idx = (int)((t >> 6) & 15);  // kc*2 + n0
  int kt = (int)((t >> 10) & 63);
  int b = (int)(t >> 16);
  int kc = idx >> 1, n0 = idx & 1;
  int g = lane >> 4, l = lane & 15;
  const float* s = p + ((size_t)b * 2049 + kt * 32 + n0 * 16 + l) * 256 + kc * 32 + g * 8;
  float4 a = *(const float4*)s;
  float4 c = *(const float4*)(s + 4);
  short8 o;
  o[0] = (short)f2b(a.x); o[1] = (short)f2b(a.y); o[2] = (short)f2b(a.z); o[3] = (short)f2b(a.w);
  o[4] = (short)f2b(c.x); o[5] = (short)f2b(c.y); o[6] = (short)f2b(c.z); o[7] = (short)f2b(c.w);
  *(short8*)(dst + t * 8) = o;
}

// ---------- pre-pass 3: fold W_o over heads -> bf16 Wsum [256][256] row-major ----------
__global__ void fold_w_kernel(const float* __restrict__ w, unsigned short* __restrict__ dst) {
  int d = blockIdx.x;    // 256
  int c = threadIdx.x;   // 256
  const float* row = w + (size_t)d * 2048 + c;
  float s = 0.f;
#pragma unroll
  for (int h = 0; h < 8; ++h) s += row[h * 256];
  dst[d * 256 + c] = f2b(s);
}

// ---------- main kernel ----------
// grid 512: b = bid&7 (XCD), pr = bid>>3 (0..63), t32 = pr<32 ? pr : 95-pr (pairing).
// Block: 32 q-rows, 4 waves = (qh, z). Per k-step: QK quarter per wave (8 MFMA),
// exp quarter, P-exchange barrier, PV d-half per wave (8 MFMA).
// LDS: [0,65536) dbuf s*32768: K 16KB + E 16KB (fragment-linear, lane-linear reads);
//      [65536,68096) P [2 qh][16][40] bf16; [68096,68352) dsum exchange [2][2][16] f32;
//      epilogue overlay: PY [32][260] bf16 at 0 (16640 B).
#define SMEM_BYTES 68352

__device__ __forceinline__ void stage_tile(char* smem, int s, int b, int kt, int tid,
                                           const unsigned short* kperm,
                                           const unsigned short* eperm) {
  const size_t cb = (size_t)(b * 64 + kt) * 8192;  // chunk start (ushorts); chunk = 16KB
  char* kd = smem + s * 32768;
  const char* ks = (const char*)(kperm + cb);
  const char* es = (const char*)(eperm + cb);
  const int wv64 = tid & ~63;  // wave-uniform: gload_lds LDS dest = uniform base, HW adds lane*16
#pragma unroll
  for (int j = 0; j < 4; ++j) {
    GLOAD_LDS16(ks + (j * 256 + tid) * 16, kd + (j * 256 + wv64) * 16);
    GLOAD_LDS16(es + (j * 256 + tid) * 16, kd + 16384 + (j * 256 + wv64) * 16);
  }
}

__global__ __launch_bounds__(256, 2) void attn_main_kernel(const unsigned short* __restrict__ pbf,
                                                           const unsigned short* __restrict__ kperm,
                                                           const unsigned short* __restrict__ eperm,
                                                           const unsigned short* __restrict__ wsum,
                                                           float* __restrict__ out) {
  __shared__ char smem[SMEM_BYTES];
  const int b = blockIdx.x & 7;
  const int pr = blockIdx.x >> 3;
  const int t32 = (pr < 32) ? pr : 95 - pr;
  const int qbase = t32 * 32;
  const int nkt = t32 + 1;              // causal k-tiles (32 wide)
  const int tid = threadIdx.x;
  const int wave = tid >> 6;
  const int lane = tid & 63;
  const int qh = wave >> 1;             // q-half: rows [qh*16, qh*16+16)
  const int z = wave & 1;               // work-half: QK n0 / PV+epilogue d-half
  const int g = lane >> 4;
  const int l = lane & 15;
  const f32x4 zero = {0.f, 0.f, 0.f, 0.f};

  // Q frags: qf[kc][i] = Q[qbase + qh*16 + l][kc*32 + g*8 + i]   (q = p[:,1:,:])
  short8 qf[8];
  {
    const unsigned short* qrow = pbf + ((size_t)b * 2049 + qbase + qh * 16 + l + 1) * 256;
#pragma unroll
    for (int kc = 0; kc < 8; ++kc) qf[kc] = *(const short8*)(qrow + kc * 32 + g * 8);
  }

  f32x4 yacc[8];
#pragma unroll
  for (int i = 0; i < 8; ++i) yacc[i] = zero;
  float dsum[4] = {0.f, 0.f, 0.f, 0.f};

  unsigned short* pp = (unsigned short*)(smem + 65536 + qh * 1280);  // P [16][40] per qh
  const int qrow0 = qbase + qh * 16 + g * 4;

  stage_tile(smem, 0, b, 0, tid, kperm, eperm);
  asm volatile("s_waitcnt vmcnt(0)" ::: "memory");
  __builtin_amdgcn_s_barrier();

  for (int kt = 0; kt < nkt; ++kt) {
    const int cur = kt & 1;
    if (kt + 1 < nkt) stage_tile(smem, cur ^ 1, b, kt + 1, tid, kperm, eperm);  // fly under compute

    // QK quarter: S[qh 16 rows][z 16 cols]; B-frags lane-linear from staged K
    const char* kb = smem + cur * 32768;
    f32x4 sacc = zero;
#pragma unroll
    for (int kc = 0; kc < 8; ++kc) {
      short8 kf = *(const short8*)(kb + (kc * 2 + z) * 1024 + lane * 16);
      sacc = __builtin_amdgcn_mfma_f32_16x16x32_bf16(qf[kc], kf, sacc, 0, 0, 0);
    }
    // weights: w = exp(clip(s/16)), causal mask; additive partials
    const int kg = kt * 32 + z * 16 + l;
#pragma unroll
    for (int jj = 0; jj < 4; ++jj) {
      float s = sacc[jj] * 0.0625f;
      s = fminf(fmaxf(s, -10.f), 10.f);
      float w = (kg <= qrow0 + jj) ? __expf(s) : 0.f;
      dsum[jj] += w;
      pp[(g * 4 + jj) * 40 + z * 16 + l] = f2b(w);
    }
    // P-exchange barrier: own LDS writes visible, staging loads stay in flight (no vmcnt drain)
    asm volatile("s_waitcnt lgkmcnt(0)" ::: "memory");
    __builtin_amdgcn_s_barrier();
    __builtin_amdgcn_sched_barrier(0);

    // PV: A = P[qh] full 32k, B = staged E frags (d-half z)
    short8 af = *(const short8*)(pp + l * 40 + g * 8);
    const char* eb = smem + cur * 32768 + 16384;
#pragma unroll
    for (int dd = 0; dd < 8; ++dd) {
      short8 ef = *(const short8*)(eb + (z * 8 + dd) * 1024 + lane * 16);
      yacc[dd] = __builtin_amdgcn_mfma_f32_16x16x32_bf16(af, ef, yacc[dd], 0, 0, 0);
    }
    // end-of-step: staged buffer complete (vmcnt) + own reads retired (lgkm), then barrier
    asm volatile("s_waitcnt vmcnt(0) lgkmcnt(0)" ::: "memory");
    __builtin_amdgcn_s_barrier();
  }

  // denominators: reduce over the 16 l-lanes, exchange across z halves
#pragma unroll
  for (int jj = 0; jj < 4; ++jj) {
    float v = dsum[jj];
    v += __shfl_xor(v, 1);
    v += __shfl_xor(v, 2);
    v += __shfl_xor(v, 4);
    v += __shfl_xor(v, 8);
    dsum[jj] = v;
  }
  float* dx = (float*)(smem + 68096);  // [2 qh][2 z][16]
  if (l == 0) {
#pragma unroll
    for (int jj = 0; jj < 4; ++jj) dx[(qh * 2 + z) * 16 + g * 4 + jj] = dsum[jj];
  }
  __syncthreads();

  // normalize + write PY bf16 [32][260] (overlays dbuf; all PV reads retired at loop barrier)
  unsigned short* py = (unsigned short*)smem;
  {
    float inv[4];
#pragma unroll
    for (int jj = 0; jj < 4; ++jj) {
      float dtot = dx[(qh * 2) * 16 + g * 4 + jj] + dx[(qh * 2 + 1) * 16 + g * 4 + jj];
      inv[jj] = 1.f / (dtot * (float)(qrow0 + jj + 1));  // softmax denom * row_scale
    }
#pragma unroll
    for (int dd = 0; dd < 8; ++dd) {
#pragma unroll
      for (int jj = 0; jj < 4; ++jj)
        py[(qh * 16 + g * 4 + jj) * 260 + (z * 8 + dd) * 16 + l] = f2b(yacc[dd][jj] * inv[jj]);
    }
  }
  __syncthreads();

  // epilogue: out[q][d] = sum_d' y_norm[q][d'] * Wsum[d][d']; wave covers d0 = z*8..+8
  {
    f32x4 oacc[8];
#pragma unroll
    for (int i = 0; i < 8; ++i) oacc[i] = zero;
#pragma unroll
    for (int kc = 0; kc < 8; ++kc) {
      short8 a2 = *(const short8*)(py + (qh * 16 + l) * 260 + kc * 32 + g * 8);
#pragma unroll
      for (int dd = 0; dd < 8; ++dd) {
        short8 wf =
            *(const short8*)(wsum + (size_t)((z * 8 + dd) * 16 + l) * 256 + kc * 32 + g * 8);
        oacc[dd] = __builtin_amdgcn_mfma_f32_16x16x32_bf16(a2, wf, oacc[dd], 0, 0, 0);
      }
    }
#pragma unroll
    for (int dd = 0; dd < 8; ++dd) {
#pragma unroll
      for (int jj = 0; jj < 4; ++jj) {
        const int d = (z * 8 + dd) * 16 + l;
        out[((size_t)b * 2048 + qbase + qh * 16 + g * 4 + jj) * 256 + d] = oacc[dd][jj];
      }
    }
  }
}

extern "C" void kernel_launch(void* const* d_in, const int* in_sizes, int n_in, void* d_out,
                              int out_size, void* d_ws, size_t ws_size, hipStream_t stream) {
  (void)in_sizes; (void)n_in; (void)out_size; (void)ws_size;
  const float* e = (const float*)d_in[0];    // [8][2048][256]
  const float* p = (const float*)d_in[1];    // [8][2049][256]
  const float* Wo = (const float*)d_in[2];   // [256][2048]
  float* out = (float*)d_out;                // [8][2048][256] f32

  unsigned short* pbf = (unsigned short*)d_ws;                        // 8,392,704 B
  unsigned short* eperm = (unsigned short*)((char*)d_ws + 8392704);   // 8,388,608 B
  unsigned short* kperm = (unsigned short*)((char*)d_ws + 16781312);  // 8,388,608 B
  unsigned short* wsum = (unsigned short*)((char*)d_ws + 25169920);   // 131,072 B

  hipLaunchKernelGGL(cvt_p_kernel, dim3(2049), dim3(256), 0, stream, p, pbf);
  hipLaunchKernelGGL(perm_e_kernel, dim3(2048), dim3(256), 0, stream, e, eperm);
  hipLaunchKernelGGL(perm_k_kernel, dim3(2048), dim3(256), 0, stream, p, kperm);
  hipLaunchKernelGGL(fold_w_kernel, dim3(256), dim3(256), 0, stream, Wo, wsum);
  hipLaunchKernelGGL(attn_main_kernel, dim3(512), dim3(256), 0, stream, pbf, kperm, eperm, wsum,
                     out);
}